// Round 4
// baseline (698.261 us; speedup 1.0000x reference)
//
#include <hip/hip_runtime.h>

typedef unsigned short u16;
typedef __attribute__((ext_vector_type(8))) short short8;
typedef __attribute__((ext_vector_type(4))) float f32x4;
typedef __attribute__((ext_vector_type(8))) unsigned short ushort8;
typedef __attribute__((ext_vector_type(4))) unsigned short ushort4v;

__device__ __forceinline__ u16 f2bf(float f) {
    unsigned int u = __float_as_uint(f);
    u += 0x7FFFu + ((u >> 16) & 1u);   // round-to-nearest-even
    return (u16)(u >> 16);
}
__device__ __forceinline__ float bf2f(u16 h) {
    return __uint_as_float(((unsigned int)h) << 16);
}

// ---------------------------------------------------------------------------
// Barrier-free, LDS-free GEMM:  C = alpha * A[M,K] * B[N,K]^T, bf16 inputs.
// Round-3 analysis: the 2-barrier global_load_lds structure was DMA-bound
// (~22 B/cyc/CU fill ceiling, no overlap with compute inside a block,
// ~2.4 blocks resident -> MfmaUtil stuck at 20-23%).  Here every wave loads
// its MFMA fragments DIRECTLY from global: a wave's 16B/lane load covers
// 16 x 64B segments (L1-friendly); intra-block 2x duplication is absorbed
// by L1, inter-block tile reuse by L2 (~13 TB/s needed vs 34.5 ceiling).
// No __syncthreads anywhere: 12 waves/CU free-run, latency hidden by TLP,
// K-loop unrolled 4x with immediate-folded offsets.
//
// Tile 128x128, 4 waves, each wave a 64x64 quadrant = 4x4 MFMA 16x16x32.
//
// MODE 0: fused QKV projection. A=xbf[16384,768], B=wt[2304,768] (3 W^T).
// MODE 1: logits S_b = 0.125 * Q_b K_b^T  (batch == XCD, panels of 4).
// MODE 2: out_b = A_b V_b (A=probs bf16, B=V^T), fp32 out (panels of 2).
// ---------------------------------------------------------------------------
template <int MODE>
__global__ __launch_bounds__(256, 3) void gemm_bt(
    const u16* __restrict__ A, const u16* __restrict__ B,
    void* __restrict__ O0, void* __restrict__ O1, void* __restrict__ O2,
    float alpha)
{
    constexpr int K   = (MODE == 2) ? 2048 : 768;
    constexpr int lda = (MODE == 2) ? 2048 : 768;
    constexpr int ldb = (MODE == 2) ? 2048 : 768;

    const int f = blockIdx.x;
    const int xcd = f & 7;
    const int u = f >> 3;

    int tm, bn, cn, which = 0;
    long aoff = 0, boff = 0;
    if constexpr (MODE == 0) {
        const int c = u >> 4;            // 0..17
        const int rl = u & 15;
        tm = (xcd * 16 + rl) * 128;
        bn = c * 128;
        which = c / 6;
        cn = (c % 6) * 128;
    } else if constexpr (MODE == 1) {
        const int p = u >> 6, t = u & 63, c = t >> 2, rl = t & 3;
        tm = (p * 4 + rl) * 128;
        bn = cn = c * 128;
        aoff = (long)xcd * 2048 * 768;
        boff = aoff;
    } else {
        const int p = u / 12, t = u % 12, c = t >> 1, rl = t & 1;
        tm = (p * 2 + rl) * 128;
        bn = cn = c * 128;
        aoff = (long)xcd * 2048 * 2048;
        boff = (long)xcd * 768 * 2048;
    }

    const int tid  = threadIdx.x;
    const int lane = tid & 63;
    const int wave = tid >> 6;
    const int wr = wave >> 1;
    const int wc = wave & 1;
    const int q  = lane >> 4;      // k-chunk quarter
    const int r  = lane & 15;      // row within 16

    // Per-lane fragment pointers (A-frag: row=lane&15, k=q*8+e  — verified
    // operand layout for mfma_f32_16x16x32_bf16; same C/D layout as before).
    const u16* ap[4];
    const u16* bp[4];
#pragma unroll
    for (int i = 0; i < 4; ++i)
        ap[i] = A + aoff + (long)(tm + wr * 64 + i * 16 + r) * lda + q * 8;
#pragma unroll
    for (int j = 0; j < 4; ++j)
        bp[j] = B + boff + (long)(bn + wc * 64 + j * 16 + r) * ldb + q * 8;

    f32x4 acc[4][4] = {};

    for (int k0 = 0; k0 < K; k0 += 128) {
#pragma unroll
        for (int kk = 0; kk < 128; kk += 32) {
            short8 a[4], b[4];
#pragma unroll
            for (int i = 0; i < 4; ++i) a[i] = *(const short8*)(ap[i] + k0 + kk);
#pragma unroll
            for (int j = 0; j < 4; ++j) b[j] = *(const short8*)(bp[j] + k0 + kk);
#pragma unroll
            for (int i = 0; i < 4; ++i)
#pragma unroll
                for (int j = 0; j < 4; ++j)
                    acc[i][j] = __builtin_amdgcn_mfma_f32_16x16x32_bf16(
                        a[i], b[j], acc[i][j], 0, 0, 0);
        }
    }

    // Epilogue. C/D layout: col = lane&15, row = (lane>>4)*4 + r
#pragma unroll
    for (int i = 0; i < 4; ++i) {
        const int row0 = tm + wr * 64 + i * 16 + ((lane >> 4) << 2);
#pragma unroll
        for (int j = 0; j < 4; ++j) {
            const int col = cn + wc * 64 + j * 16 + (lane & 15);
#pragma unroll
            for (int rr = 0; rr < 4; ++rr) {
                const int row = row0 + rr;
                const float val = acc[i][j][rr] * alpha;
                if constexpr (MODE == 0) {
                    if (which == 0)
                        ((u16*)O0)[(long)row * 768 + col] = f2bf(val);
                    else if (which == 1)
                        ((u16*)O1)[(long)row * 768 + col] = f2bf(val);
                    else  // V^T: [b, col, s]
                        ((u16*)O2)[((long)(row >> 11) * 768 + col) * 2048 + (row & 2047)] = f2bf(val);
                } else if constexpr (MODE == 1) {
                    ((u16*)O0)[(long)xcd * 2048 * 2048 + (long)row * 2048 + col] = f2bf(val);
                } else {
                    ((float*)O0)[(long)xcd * 2048 * 768 + (long)row * 768 + col] = val;
                }
            }
        }
    }
}

// ---------------------------------------------------------------------------
__global__ __launch_bounds__(256) void cvt_x_kernel(
    const float4* __restrict__ x, ushort4v* __restrict__ out, int n4)
{
    int i = blockIdx.x * 256 + threadIdx.x;
    if (i < n4) {
        float4 f = x[i];
        ushort4v o;
        o.x = f2bf(f.x); o.y = f2bf(f.y); o.z = f2bf(f.z); o.w = f2bf(f.w);
        out[i] = o;
    }
}

// w[3][768][768] (m,d,o)  ->  wt[3][768][768] (m,o,d), bf16
__global__ __launch_bounds__(256) void cvt_w_kernel(
    const float* __restrict__ w, u16* __restrict__ wt)
{
    int i = blockIdx.x * 256 + threadIdx.x;   // total 3*768*768
    int d = i % 768;
    int o = (i / 768) % 768;
    int m = i / (768 * 768);
    wt[i] = f2bf(w[((long)m * 768 + d) * 768 + o]);
}

// one block per row, 2048 bf16 logits in-place -> softmax probs (bf16)
__global__ __launch_bounds__(256) void softmax_kernel(u16* __restrict__ S)
{
    const long row = blockIdx.x;
    u16* p = S + row * 2048;
    const int t = threadIdx.x;
    const int lane = t & 63;
    const int wave = t >> 6;
    __shared__ float red[8];

    ushort8 raw = *(const ushort8*)(p + t * 8);
    float v[8];
    float m = -1e30f;
#pragma unroll
    for (int i = 0; i < 8; ++i) { v[i] = bf2f(raw[i]); m = fmaxf(m, v[i]); }
#pragma unroll
    for (int off = 1; off < 64; off <<= 1) m = fmaxf(m, __shfl_xor(m, off, 64));
    if (lane == 0) red[wave] = m;
    __syncthreads();
    m = fmaxf(fmaxf(red[0], red[1]), fmaxf(red[2], red[3]));

    float s = 0.f;
#pragma unroll
    for (int i = 0; i < 8; ++i) { v[i] = __expf(v[i] - m); s += v[i]; }
#pragma unroll
    for (int off = 1; off < 64; off <<= 1) s += __shfl_xor(s, off, 64);
    if (lane == 0) red[4 + wave] = s;
    __syncthreads();
    s = (red[4] + red[5]) + (red[6] + red[7]);

    const float inv = 1.0f / s;
    ushort8 out;
#pragma unroll
    for (int i = 0; i < 8; ++i) out[i] = f2bf(v[i] * inv);
    *(ushort8*)(p + t * 8) = out;
}

// ---------------------------------------------------------------------------
extern "C" void kernel_launch(void* const* d_in, const int* in_sizes, int n_in,
                              void* d_out, int out_size, void* d_ws, size_t ws_size,
                              hipStream_t stream)
{
    const float* x  = (const float*)d_in[0];   // [8,2048,768]
    const float* wk = (const float*)d_in[1];   // [3,768,768]
    float* out = (float*)d_out;                // [8,2048,768]

    char* ws = (char*)d_ws;
    u16* xbf = (u16*)(ws);                       // 16384x768        25.2 MB
    u16* wt  = (u16*)(ws + 25165824);            // 3x768x768 (W^T)   3.5 MB
    u16* qbf = (u16*)(ws + 28704768);            // 16384x768        25.2 MB
    u16* kbf = (u16*)(ws + 53870592);            // 16384x768        25.2 MB
    u16* vt  = (u16*)(ws + 79036416);            // 8x768x2048       25.2 MB
    u16* S   = (u16*)(ws + 104202240);           // 8x2048x2048      67.1 MB

    // 1. conversions
    cvt_x_kernel<<<dim3(12288), dim3(256), 0, stream>>>(
        (const float4*)x, (ushort4v*)xbf, 3145728);
    cvt_w_kernel<<<dim3(6912), dim3(256), 0, stream>>>(wk, wt);

    // 2. fused QKV projections (one dispatch, 18 col-tiles share x row-tiles)
    gemm_bt<0><<<dim3(2304), dim3(256), 0, stream>>>(
        xbf, wt, qbf, kbf, vt, 1.0f);

    // 3. logits: S_b = 0.125 * Q_b K_b^T   (batch <-> XCD)
    gemm_bt<1><<<dim3(2048), dim3(256), 0, stream>>>(
        qbf, kbf, S, nullptr, nullptr, 0.125f);

    // 4. softmax rows (in place, bf16)
    softmax_kernel<<<dim3(16384), dim3(256), 0, stream>>>(S);

    // 5. out_b = A_b V_b
    gemm_bt<2><<<dim3(768), dim3(256), 0, stream>>>(
        S, vt, out, nullptr, nullptr, 1.0f);
}

// Round 5
// 375.183 us; speedup vs baseline: 1.8611x; 1.8611x over previous
//
#include <hip/hip_runtime.h>

typedef unsigned short u16;
typedef __attribute__((ext_vector_type(8))) short short8;
typedef __attribute__((ext_vector_type(4))) float f32x4;
typedef __attribute__((ext_vector_type(8))) unsigned short ushort8;
typedef __attribute__((ext_vector_type(4))) unsigned short ushort4v;

__device__ __forceinline__ u16 f2bf(float f) {
    unsigned int u = __float_as_uint(f);
    u += 0x7FFFu + ((u >> 16) & 1u);   // round-to-nearest-even
    return (u16)(u >> 16);
}
__device__ __forceinline__ float bf2f(u16 h) {
    return __uint_as_float(((unsigned int)h) << 16);
}

// ---------------------------------------------------------------------------
// Software-pipelined GEMM:  C = alpha * A[M,K] * B[N,K]^T, bf16 inputs.
// Round 2-4 ladder: global_load_lds DMA path caps at ~12 B/cyc/CU (2-barrier
// drain) -> 19.5% peak; LDS-free direct loads thrash L1 -> 10%.  This version
// stages through REGISTERS (buffer_load -> VGPR -> ds_write), double-buffered
// LDS, ONE raw s_barrier per iter (lgkmcnt(0) only - vmcnt stays in flight
// across the barrier, hipBLASLt-style).  Load of tile k+1 issues before the
// barrier and is first consumed by next iter's ds_write -> a full compute
// phase of slack hides L2 latency.
//
// Tile 128x128, BK=32, 4 waves, 4x4 MFMA 16x16x32 per wave.
// LDS XOR swizzle (round-2 verified, 0 conflicts): chunk (row,kc) at granule
// row*4 + (kc ^ ((row>>1)&3)); global side permutes within each 64B row
// segment (coalescing kept).
//
// MODE 0: fused QKV projection. A=xbf[16384,768], B=wt[2304,768] (3 W^T).
//         xcd = blk&7 owns x row-tiles [16*xcd,16*(xcd+1)); FETCH ideal (r2).
// MODE 1: logits S_b = 0.125 * Q_b K_b^T  (batch == XCD, panels of 4).
// MODE 2: out_b = A_b V_b (A=probs bf16, B=V^T), fp32 out (panels of 2).
// ---------------------------------------------------------------------------
template <int MODE>
__global__ __launch_bounds__(256, 3) void gemm_bt(
    const u16* __restrict__ A, const u16* __restrict__ B,
    void* __restrict__ O0, void* __restrict__ O1, void* __restrict__ O2,
    float alpha)
{
    constexpr int K   = (MODE == 2) ? 2048 : 768;
    constexpr int lda = (MODE == 2) ? 2048 : 768;
    constexpr int ldb = (MODE == 2) ? 2048 : 768;
    constexpr int ITERS = K / 32;

    __shared__ uint4 sA[2][512];   // 2 x 8 KB
    __shared__ uint4 sB[2][512];   // 2 x 8 KB

    const int f = blockIdx.x;
    const int xcd = f & 7;
    const int u = f >> 3;

    int tm, bn, cn, which = 0;
    long aoff = 0, boff = 0;
    if constexpr (MODE == 0) {
        const int c = u >> 4;            // 0..17
        const int rl = u & 15;
        tm = (xcd * 16 + rl) * 128;
        bn = c * 128;
        which = c / 6;
        cn = (c % 6) * 128;
    } else if constexpr (MODE == 1) {
        const int p = u >> 6, t = u & 63, c = t >> 2, rl = t & 3;
        tm = (p * 4 + rl) * 128;
        bn = cn = c * 128;
        aoff = (long)xcd * 2048 * 768;
        boff = aoff;
    } else {
        const int p = u / 12, t = u % 12, c = t >> 1, rl = t & 1;
        tm = (p * 2 + rl) * 128;
        bn = cn = c * 128;
        aoff = (long)xcd * 2048 * 2048;
        boff = (long)xcd * 768 * 2048;
    }

    const int tid  = threadIdx.x;
    const int lane = tid & 63;
    const int wave = tid >> 6;
    const int wr = wave >> 1;
    const int wc = wave & 1;

    f32x4 acc[4][4] = {};

    // staging slots: s0=tid, s1=tid+256; slot s <- global chunk
    // (row = s>>2, kc = (s&3) ^ ((row>>1)&3))
    const int s0 = tid, s1 = tid + 256;
    const int r0 = s0 >> 2, kc0 = (s0 & 3) ^ ((r0 >> 1) & 3);
    const int r1 = s1 >> 2, kc1 = (s1 & 3) ^ ((r1 >> 1) & 3);
    const uint4* gA0 = (const uint4*)(A + aoff) + ((long)(tm + r0) * lda + kc0 * 8) / 8;
    const uint4* gA1 = (const uint4*)(A + aoff) + ((long)(tm + r1) * lda + kc1 * 8) / 8;
    const uint4* gB0 = (const uint4*)(B + boff) + ((long)(bn + r0) * ldb + kc0 * 8) / 8;
    const uint4* gB1 = (const uint4*)(B + boff) + ((long)(bn + r1) * ldb + kc1 * 8) / 8;

    // read-side swizzle (constant per lane)
    const int swz = ((lane >> 4) ^ ((lane >> 1) & 3)) * 8;
    const int a_row = (wr * 64 + (lane & 15)) * 32;
    const int b_row = (wc * 64 + (lane & 15)) * 32;

    // prologue: tile 0 -> regs
    uint4 ra0 = gA0[0], ra1 = gA1[0], rb0 = gB0[0], rb1 = gB1[0];

#pragma unroll 2
    for (int it = 0; it < ITERS; ++it) {
        const int buf = it & 1;
        // write tile `it` (regs) to LDS buf — safe: all ds_reads of this buf
        // (iter it-2) retired before any wave passed barrier(it-1), because
        // the barrier asm waits lgkmcnt(0) before signaling.
        sA[buf][s0] = ra0;  sA[buf][s1] = ra1;
        sB[buf][s0] = rb0;  sB[buf][s1] = rb1;
        // issue loads for tile it+1 (stay in flight across the barrier;
        // first consumed by next iter's ds_write)
        const int nk = (it + 1 < ITERS) ? (it + 1) * 4 : it * 4;
        ra0 = gA0[nk];  ra1 = gA1[nk];  rb0 = gB0[nk];  rb1 = gB1[nk];
        // LDS writes visible to the workgroup; vmcnt NOT drained.
        asm volatile("s_waitcnt lgkmcnt(0)\n\ts_barrier" ::: "memory");

        const u16* a_base = (const u16*)&sA[buf][0] + a_row + swz;
        const u16* b_base = (const u16*)&sB[buf][0] + b_row + swz;
        short8 a[4], b[4];
#pragma unroll
        for (int i = 0; i < 4; ++i) a[i] = *(const short8*)(a_base + i * 16 * 32);
#pragma unroll
        for (int j = 0; j < 4; ++j) b[j] = *(const short8*)(b_base + j * 16 * 32);
#pragma unroll
        for (int i = 0; i < 4; ++i)
#pragma unroll
            for (int j = 0; j < 4; ++j)
                acc[i][j] = __builtin_amdgcn_mfma_f32_16x16x32_bf16(
                    a[i], b[j], acc[i][j], 0, 0, 0);
    }

    // Epilogue. C/D layout: col = lane&15, row = (lane>>4)*4 + r
#pragma unroll
    for (int i = 0; i < 4; ++i) {
        const int row0 = tm + wr * 64 + i * 16 + ((lane >> 4) << 2);
#pragma unroll
        for (int j = 0; j < 4; ++j) {
            const int col = cn + wc * 64 + j * 16 + (lane & 15);
#pragma unroll
            for (int rr = 0; rr < 4; ++rr) {
                const int row = row0 + rr;
                const float val = acc[i][j][rr] * alpha;
                if constexpr (MODE == 0) {
                    if (which == 0)
                        ((u16*)O0)[(long)row * 768 + col] = f2bf(val);
                    else if (which == 1)
                        ((u16*)O1)[(long)row * 768 + col] = f2bf(val);
                    else  // V^T: [b, col, s]
                        ((u16*)O2)[((long)(row >> 11) * 768 + col) * 2048 + (row & 2047)] = f2bf(val);
                } else if constexpr (MODE == 1) {
                    ((u16*)O0)[(long)xcd * 2048 * 2048 + (long)row * 2048 + col] = f2bf(val);
                } else {
                    ((float*)O0)[(long)xcd * 2048 * 768 + (long)row * 768 + col] = val;
                }
            }
        }
    }
}

// ---------------------------------------------------------------------------
__global__ __launch_bounds__(256) void cvt_x_kernel(
    const float4* __restrict__ x, ushort4v* __restrict__ out, int n4)
{
    int i = blockIdx.x * 256 + threadIdx.x;
    if (i < n4) {
        float4 f = x[i];
        ushort4v o;
        o.x = f2bf(f.x); o.y = f2bf(f.y); o.z = f2bf(f.z); o.w = f2bf(f.w);
        out[i] = o;
    }
}

// w[3][768][768] (m,d,o)  ->  wt[3][768][768] (m,o,d), bf16
__global__ __launch_bounds__(256) void cvt_w_kernel(
    const float* __restrict__ w, u16* __restrict__ wt)
{
    int i = blockIdx.x * 256 + threadIdx.x;   // total 3*768*768
    int d = i % 768;
    int o = (i / 768) % 768;
    int m = i / (768 * 768);
    wt[i] = f2bf(w[((long)m * 768 + d) * 768 + o]);
}

// one block per row, 2048 bf16 logits in-place -> softmax probs (bf16)
__global__ __launch_bounds__(256) void softmax_kernel(u16* __restrict__ S)
{
    const long row = blockIdx.x;
    u16* p = S + row * 2048;
    const int t = threadIdx.x;
    const int lane = t & 63;
    const int wave = t >> 6;
    __shared__ float red[8];

    ushort8 raw = *(const ushort8*)(p + t * 8);
    float v[8];
    float m = -1e30f;
#pragma unroll
    for (int i = 0; i < 8; ++i) { v[i] = bf2f(raw[i]); m = fmaxf(m, v[i]); }
#pragma unroll
    for (int off = 1; off < 64; off <<= 1) m = fmaxf(m, __shfl_xor(m, off, 64));
    if (lane == 0) red[wave] = m;
    __syncthreads();
    m = fmaxf(fmaxf(red[0], red[1]), fmaxf(red[2], red[3]));

    float s = 0.f;
#pragma unroll
    for (int i = 0; i < 8; ++i) { v[i] = __expf(v[i] - m); s += v[i]; }
#pragma unroll
    for (int off = 1; off < 64; off <<= 1) s += __shfl_xor(s, off, 64);
    if (lane == 0) red[4 + wave] = s;
    __syncthreads();
    s = (red[4] + red[5]) + (red[6] + red[7]);

    const float inv = 1.0f / s;
    ushort8 out;
#pragma unroll
    for (int i = 0; i < 8; ++i) out[i] = f2bf(v[i] * inv);
    *(ushort8*)(p + t * 8) = out;
}

// ---------------------------------------------------------------------------
extern "C" void kernel_launch(void* const* d_in, const int* in_sizes, int n_in,
                              void* d_out, int out_size, void* d_ws, size_t ws_size,
                              hipStream_t stream)
{
    const float* x  = (const float*)d_in[0];   // [8,2048,768]
    const float* wk = (const float*)d_in[1];   // [3,768,768]
    float* out = (float*)d_out;                // [8,2048,768]

    char* ws = (char*)d_ws;
    u16* xbf = (u16*)(ws);                       // 16384x768        25.2 MB
    u16* wt  = (u16*)(ws + 25165824);            // 3x768x768 (W^T)   3.5 MB
    u16* qbf = (u16*)(ws + 28704768);            // 16384x768        25.2 MB
    u16* kbf = (u16*)(ws + 53870592);            // 16384x768        25.2 MB
    u16* vt  = (u16*)(ws + 79036416);            // 8x768x2048       25.2 MB
    u16* S   = (u16*)(ws + 104202240);           // 8x2048x2048      67.1 MB

    // 1. conversions
    cvt_x_kernel<<<dim3(12288), dim3(256), 0, stream>>>(
        (const float4*)x, (ushort4v*)xbf, 3145728);
    cvt_w_kernel<<<dim3(6912), dim3(256), 0, stream>>>(wk, wt);

    // 2. fused QKV projections (one dispatch, 18 col-tiles share x row-tiles)
    gemm_bt<0><<<dim3(2304), dim3(256), 0, stream>>>(
        xbf, wt, qbf, kbf, vt, 1.0f);

    // 3. logits: S_b = 0.125 * Q_b K_b^T   (batch <-> XCD)
    gemm_bt<1><<<dim3(2048), dim3(256), 0, stream>>>(
        qbf, kbf, S, nullptr, nullptr, 0.125f);

    // 4. softmax rows (in place, bf16)
    softmax_kernel<<<dim3(16384), dim3(256), 0, stream>>>(S);

    // 5. out_b = A_b V_b
    gemm_bt<2><<<dim3(768), dim3(256), 0, stream>>>(
        S, vt, out, nullptr, nullptr, 1.0f);
}

// Round 6
// 374.899 us; speedup vs baseline: 1.8625x; 1.0008x over previous
//
#include <hip/hip_runtime.h>

typedef unsigned short u16;
typedef __attribute__((ext_vector_type(8))) short short8;
typedef __attribute__((ext_vector_type(16))) float f32x16;
typedef __attribute__((ext_vector_type(8))) unsigned short ushort8;
typedef __attribute__((ext_vector_type(4))) unsigned short ushort4v;

__device__ __forceinline__ u16 f2bf(float f) {
    unsigned int u = __float_as_uint(f);
    u += 0x7FFFu + ((u >> 16) & 1u);   // round-to-nearest-even
    return (u16)(u >> 16);
}
__device__ __forceinline__ float bf2f(u16 h) {
    return __uint_as_float(((unsigned int)h) << 16);
}

// ---------------------------------------------------------------------------
// Software-pipelined GEMM, 32x32x16 MFMA:  C = alpha*A[M,K]*B[N,K]^T, bf16.
// Round 2/3/5 invariant: ~480 TF regardless of staging structure. Per-SIMD
// arithmetic (m06): one 16x16x32 MFMA = 19.4 SIMD-cyc -> 16 instr/wave-iter
// = 310 cyc vs wall ~1300 -> issue/wait-bound with ~2.7 waves/SIMD.
// This version: (1) 32x32x16 shape - halves MFMA+LDS instruction count per
// iter (8+8 vs 16+8) and runs the faster pipe (2495 vs 2075 TF ceiling);
// (2) LDS rows padded to 80 B (possible because reg-staging ds_write has
// free addressing) so the 32x32 frag reads are 2-way/free without global-
// side XOR; (3) launch_bounds(256,4): 64 arch + 64 acc = 128 regs exactly
// -> 4 waves/SIMD, LDS 40KB -> 4 blocks/CU.
// Pipeline: buffer_load->VGPR (tile k+1 in flight across the barrier,
// hipBLASLt-style), ds_write tile k, ONE raw s_barrier (lgkmcnt(0) only).
//
// Tile 128x128, BK=32, 4 waves, each wave 64x64 = 2x2 of 32x32x16, acc 64 AGPR.
//
// MODE 0: fused QKV projection. A=xbf[16384,768], B=wt[2304,768] (3 W^T).
// MODE 1: logits S_b = 0.125 * Q_b K_b^T  (batch == XCD, panels of 4).
// MODE 2: out_b = A_b V_b (A=probs bf16, B=V^T), fp32 out (panels of 2).
// ---------------------------------------------------------------------------
template <int MODE>
__global__ __launch_bounds__(256, 4) void gemm_bt(
    const u16* __restrict__ A, const u16* __restrict__ B,
    void* __restrict__ O0, void* __restrict__ O1, void* __restrict__ O2,
    float alpha)
{
    constexpr int K   = (MODE == 2) ? 2048 : 768;
    constexpr int lda = (MODE == 2) ? 2048 : 768;
    constexpr int ldb = (MODE == 2) ? 2048 : 768;
    constexpr int ITERS = K / 32;
    constexpr int LDR = 40;            // u16 per LDS row (80 B, padded)

    __shared__ u16 sA[2][128 * LDR];   // 2 x 10 KB
    __shared__ u16 sB[2][128 * LDR];   // 2 x 10 KB

    const int f = blockIdx.x;
    const int xcd = f & 7;
    const int u = f >> 3;

    int tm, bn, cn, which = 0;
    long aoff = 0, boff = 0;
    if constexpr (MODE == 0) {
        const int c = u >> 4;            // 0..17
        const int rl = u & 15;
        tm = (xcd * 16 + rl) * 128;
        bn = c * 128;
        which = c / 6;
        cn = (c % 6) * 128;
    } else if constexpr (MODE == 1) {
        const int p = u >> 6, t = u & 63, c = t >> 2, rl = t & 3;
        tm = (p * 4 + rl) * 128;
        bn = cn = c * 128;
        aoff = (long)xcd * 2048 * 768;
        boff = aoff;
    } else {
        const int p = u / 12, t = u % 12, c = t >> 1, rl = t & 1;
        tm = (p * 2 + rl) * 128;
        bn = cn = c * 128;
        aoff = (long)xcd * 2048 * 2048;
        boff = (long)xcd * 768 * 2048;
    }

    const int tid  = threadIdx.x;
    const int lane = tid & 63;
    const int wave = tid >> 6;
    const int wr = wave >> 1;
    const int wc = wave & 1;

    f32x16 acc[2][2] = {};

    // staging: slots s0=tid, s1=tid+256; row = s>>2, kc = s&3 (coalesced).
    const int s0 = tid, s1 = tid + 256;
    const int r0 = s0 >> 2, kc0 = s0 & 3;
    const int r1 = s1 >> 2, kc1 = s1 & 3;
    const uint4* gA0 = (const uint4*)(A + aoff) + ((long)(tm + r0) * lda + kc0 * 8) / 8;
    const uint4* gA1 = (const uint4*)(A + aoff) + ((long)(tm + r1) * lda + kc1 * 8) / 8;
    const uint4* gB0 = (const uint4*)(B + boff) + ((long)(bn + r0) * ldb + kc0 * 8) / 8;
    const uint4* gB1 = (const uint4*)(B + boff) + ((long)(bn + r1) * ldb + kc1 * 8) / 8;
    const int wA0 = r0 * LDR + kc0 * 8, wA1 = r1 * LDR + kc1 * 8;

    // read offsets: A-frag for 32x32x16: row = lane&31, k = (lane>>5)*8 + e;
    // u16 index = row*LDR + s*16 + (lane>>5)*8  (byte row*80 + s*32 + hi*16)
    const int fr = (lane & 31) * LDR + (lane >> 5) * 8;
    const int a_t0 = (wr * 64) * LDR + fr;
    const int b_t0 = (wc * 64) * LDR + fr;

    // prologue: tile 0 -> regs
    uint4 ra0 = gA0[0], ra1 = gA1[0], rb0 = gB0[0], rb1 = gB1[0];

#pragma unroll 2
    for (int it = 0; it < ITERS; ++it) {
        const int buf = it & 1;
        // write tile `it` to LDS buf (safe: own reads of this buf retired
        // before own barrier(it-1) via lgkmcnt(0); siblings at most 1 behind
        // and only touch the other buffer)
        *(uint4*)&sA[buf][wA0] = ra0;  *(uint4*)&sA[buf][wA1] = ra1;
        *(uint4*)&sB[buf][wA0] = rb0;  *(uint4*)&sB[buf][wA1] = rb1;
        // issue loads for tile it+1 (stay in flight across the barrier)
        const int nk = (it + 1 < ITERS) ? (it + 1) * 4 : it * 4;
        ra0 = gA0[nk];  ra1 = gA1[nk];  rb0 = gB0[nk];  rb1 = gB1[nk];
        // LDS writes visible; vmcnt NOT drained.
        asm volatile("s_waitcnt lgkmcnt(0)\n\ts_barrier" ::: "memory");

#pragma unroll
        for (int s = 0; s < 2; ++s) {
            short8 a[2], b[2];
#pragma unroll
            for (int t = 0; t < 2; ++t) {
                a[t] = *(const short8*)&sA[buf][a_t0 + t * 32 * LDR + s * 16];
                b[t] = *(const short8*)&sB[buf][b_t0 + t * 32 * LDR + s * 16];
            }
#pragma unroll
            for (int t = 0; t < 2; ++t)
#pragma unroll
                for (int uu = 0; uu < 2; ++uu)
                    acc[t][uu] = __builtin_amdgcn_mfma_f32_32x32x16_bf16(
                        a[t], b[uu], acc[t][uu], 0, 0, 0);
        }
    }

    // Epilogue. 32x32 C/D layout (m74/m101): col = lane&31,
    // row = (reg&3) + 8*(reg>>2) + 4*(lane>>5)
#pragma unroll
    for (int t = 0; t < 2; ++t) {
#pragma unroll
        for (int uu = 0; uu < 2; ++uu) {
            const int col = cn + wc * 64 + uu * 32 + (lane & 31);
            const int rbase = tm + wr * 64 + t * 32 + ((lane >> 5) << 2);
#pragma unroll
            for (int reg = 0; reg < 16; ++reg) {
                const int row = rbase + (reg & 3) + ((reg >> 2) << 3);
                const float val = acc[t][uu][reg] * alpha;
                if constexpr (MODE == 0) {
                    if (which == 0)
                        ((u16*)O0)[(long)row * 768 + col] = f2bf(val);
                    else if (which == 1)
                        ((u16*)O1)[(long)row * 768 + col] = f2bf(val);
                    else  // V^T: [b, col, s]
                        ((u16*)O2)[((long)(row >> 11) * 768 + col) * 2048 + (row & 2047)] = f2bf(val);
                } else if constexpr (MODE == 1) {
                    ((u16*)O0)[(long)xcd * 2048 * 2048 + (long)row * 2048 + col] = f2bf(val);
                } else {
                    ((float*)O0)[(long)xcd * 2048 * 768 + (long)row * 768 + col] = val;
                }
            }
        }
    }
}

// ---------------------------------------------------------------------------
__global__ __launch_bounds__(256) void cvt_x_kernel(
    const float4* __restrict__ x, ushort4v* __restrict__ out, int n4)
{
    int i = blockIdx.x * 256 + threadIdx.x;
    if (i < n4) {
        float4 f = x[i];
        ushort4v o;
        o.x = f2bf(f.x); o.y = f2bf(f.y); o.z = f2bf(f.z); o.w = f2bf(f.w);
        out[i] = o;
    }
}

// w[3][768][768] (m,d,o)  ->  wt[3][768][768] (m,o,d), bf16
__global__ __launch_bounds__(256) void cvt_w_kernel(
    const float* __restrict__ w, u16* __restrict__ wt)
{
    int i = blockIdx.x * 256 + threadIdx.x;   // total 3*768*768
    int d = i % 768;
    int o = (i / 768) % 768;
    int m = i / (768 * 768);
    wt[i] = f2bf(w[((long)m * 768 + d) * 768 + o]);
}

// one block per row, 2048 bf16 logits in-place -> softmax probs (bf16)
__global__ __launch_bounds__(256) void softmax_kernel(u16* __restrict__ S)
{
    const long row = blockIdx.x;
    u16* p = S + row * 2048;
    const int t = threadIdx.x;
    const int lane = t & 63;
    const int wave = t >> 6;
    __shared__ float red[8];

    ushort8 raw = *(const ushort8*)(p + t * 8);
    float v[8];
    float m = -1e30f;
#pragma unroll
    for (int i = 0; i < 8; ++i) { v[i] = bf2f(raw[i]); m = fmaxf(m, v[i]); }
#pragma unroll
    for (int off = 1; off < 64; off <<= 1) m = fmaxf(m, __shfl_xor(m, off, 64));
    if (lane == 0) red[wave] = m;
    __syncthreads();
    m = fmaxf(fmaxf(red[0], red[1]), fmaxf(red[2], red[3]));

    float s = 0.f;
#pragma unroll
    for (int i = 0; i < 8; ++i) { v[i] = __expf(v[i] - m); s += v[i]; }
#pragma unroll
    for (int off = 1; off < 64; off <<= 1) s += __shfl_xor(s, off, 64);
    if (lane == 0) red[4 + wave] = s;
    __syncthreads();
    s = (red[4] + red[5]) + (red[6] + red[7]);

    const float inv = 1.0f / s;
    ushort8 out;
#pragma unroll
    for (int i = 0; i < 8; ++i) out[i] = f2bf(v[i] * inv);
    *(ushort8*)(p + t * 8) = out;
}

// ---------------------------------------------------------------------------
extern "C" void kernel_launch(void* const* d_in, const int* in_sizes, int n_in,
                              void* d_out, int out_size, void* d_ws, size_t ws_size,
                              hipStream_t stream)
{
    const float* x  = (const float*)d_in[0];   // [8,2048,768]
    const float* wk = (const float*)d_in[1];   // [3,768,768]
    float* out = (float*)d_out;                // [8,2048,768]

    char* ws = (char*)d_ws;
    u16* xbf = (u16*)(ws);                       // 16384x768        25.2 MB
    u16* wt  = (u16*)(ws + 25165824);            // 3x768x768 (W^T)   3.5 MB
    u16* qbf = (u16*)(ws + 28704768);            // 16384x768        25.2 MB
    u16* kbf = (u16*)(ws + 53870592);            // 16384x768        25.2 MB
    u16* vt  = (u16*)(ws + 79036416);            // 8x768x2048       25.2 MB
    u16* S   = (u16*)(ws + 104202240);           // 8x2048x2048      67.1 MB

    // 1. conversions
    cvt_x_kernel<<<dim3(12288), dim3(256), 0, stream>>>(
        (const float4*)x, (ushort4v*)xbf, 3145728);
    cvt_w_kernel<<<dim3(6912), dim3(256), 0, stream>>>(wk, wt);

    // 2. fused QKV projections (one dispatch, 18 col-tiles share x row-tiles)
    gemm_bt<0><<<dim3(2304), dim3(256), 0, stream>>>(
        xbf, wt, qbf, kbf, vt, 1.0f);

    // 3. logits: S_b = 0.125 * Q_b K_b^T   (batch <-> XCD)
    gemm_bt<1><<<dim3(2048), dim3(256), 0, stream>>>(
        qbf, kbf, S, nullptr, nullptr, 0.125f);

    // 4. softmax rows (in place, bf16)
    softmax_kernel<<<dim3(16384), dim3(256), 0, stream>>>(S);

    // 5. out_b = A_b V_b
    gemm_bt<2><<<dim3(768), dim3(256), 0, stream>>>(
        S, vt, out, nullptr, nullptr, 1.0f);
}